// Round 5
// baseline (22177.348 us; speedup 1.0000x reference)
//
#include <hip/hip_runtime.h>
#include <math.h>

#define QQ 512
#define NN 1000
#define HHID 1024
#define HPAD 1024   // padded row stride for h trajectories
#define CCON 128
#define G4 4000
#define LBLK 63     // ceil(1000/16) persistent blocks, 1024 thr, 1 neuron/wave

__device__ inline float wred_min(float v){ for(int o=32;o;o>>=1) v=fminf(v,__shfl_xor(v,o)); return v; }
__device__ inline float wred_max(float v){ for(int o=32;o;o>>=1) v=fmaxf(v,__shfl_xor(v,o)); return v; }
__device__ inline float wred_sum(float v){ for(int o=32;o;o>>=1) v+=__shfl_xor(v,o); return v; }

// C[M,R] = A[M,K] @ B[R,K]^T + bias1[r] + bias2[r]; A row stride = lda.
__global__ __launch_bounds__(256) void gemm_nt(
    const float* __restrict__ A, const float* __restrict__ B,
    const float* __restrict__ bias1, const float* __restrict__ bias2,
    float* __restrict__ C, int M, int K, int R, int lda) {
  __shared__ float As[16][65];
  __shared__ float Bs[16][65];
  int tid = threadIdx.x;
  int tx = tid & 15, ty = tid >> 4;
  int m0 = blockIdx.y * 64, r0 = blockIdx.x * 64;
  float acc[4][4] = {};
  for (int k0 = 0; k0 < K; k0 += 16) {
#pragma unroll
    for (int i = 0; i < 4; i++) {
      int idx = tid + 256 * i;
      int ml = idx >> 4, kl = idx & 15;
      int m = m0 + ml, k = k0 + kl;
      As[kl][ml] = (m < M && k < K) ? A[(size_t)m * lda + k] : 0.f;
      int r = r0 + ml;
      Bs[kl][ml] = (r < R && k < K) ? B[(size_t)r * K + k] : 0.f;
    }
    __syncthreads();
#pragma unroll
    for (int kk = 0; kk < 16; kk++) {
      float a[4], b[4];
#pragma unroll
      for (int i = 0; i < 4; i++) a[i] = As[kk][ty * 4 + i];
#pragma unroll
      for (int j = 0; j < 4; j++) b[j] = Bs[kk][tx * 4 + j];
#pragma unroll
      for (int i = 0; i < 4; i++)
#pragma unroll
        for (int j = 0; j < 4; j++) acc[i][j] += a[i] * b[j];
    }
    __syncthreads();
  }
#pragma unroll
  for (int i = 0; i < 4; i++) {
    int m = m0 + ty * 4 + i;
    if (m >= M) continue;
#pragma unroll
    for (int j = 0; j < 4; j++) {
      int r = r0 + tx * 4 + j;
      if (r >= R) continue;
      float v = acc[i][j];
      if (bias1) v += bias1[r];
      if (bias2) v += bias2[r];
      C[(size_t)m * R + r] = v;
    }
  }
}

// Persistent per-layer LSTM recurrence, 512 steps in one launch.
// 63 blocks x 1024 threads; wave w owns neuron n = blockIdx*16 + w (4 W_hh
// rows in 64 VGPRs). NO __syncthreads in the step loop:
//  - wave 0 polls the 63 stamped fabric flags, releases siblings via LDS go[t]
//  - each wave drains vmcnt(0) after its h store, then ds-atomics done[t];
//    the 16th wave publishes this block's flag (plain relaxed sc1 store).
// All cross-block data via relaxed agent-scope atomics (LLC-coherent, no
// fences: an agent acquire fence = buffer_inv = full L2 invalidate).
__global__ __launch_bounds__(1024, 4) void lstm_layer(
    const float* __restrict__ P,    // [QQ, G4] input-side gates (bias incl.)
    const float* __restrict__ Whh,  // [G4, NN]
    float* __restrict__ Hall,       // [QQ, HPAD]; cols 1000..1023 never written
    int* __restrict__ flag) {       // [64] zeroed before launch
  __shared__ int go[QQ];
  __shared__ int done[QQ];
  int tid = threadIdx.x;
  int wave = tid >> 6, lane = tid & 63;
  int n = blockIdx.x * 16 + wave;
  bool active = (n < NN);
  for (int i = tid; i < QQ; i += 1024) { go[i] = 0; done[i] = 0; }

  // Preload W_hh rows: wreg[q][it] = Whh[q*1000+n][it*64+lane] (0 beyond K)
  float wreg[4][16];
  if (active) {
#pragma unroll
    for (int q = 0; q < 4; q++) {
      const float* wrow = Whh + (size_t)(q * NN + n) * NN;
#pragma unroll
      for (int it = 0; it < 16; it++) {
        int k = it * 64 + lane;
        wreg[q][it] = (k < NN) ? wrow[k] : 0.f;
      }
    }
  } else {
#pragma unroll
    for (int q = 0; q < 4; q++)
#pragma unroll
      for (int it = 0; it < 16; it++) wreg[q][it] = 0.f;
  }
  __syncthreads();  // go/done initialized

  float creg = 0.f;  // cell state, register-resident for all 512 steps

  for (int t = 0; t < QQ; t++) {
    if (t > 0) {
      if (wave == 0) {
        for (;;) {
          int v = t;
          if (lane < LBLK)
            v = __hip_atomic_load(&flag[lane], __ATOMIC_RELAXED,
                                  __HIP_MEMORY_SCOPE_AGENT);
          if (__all(v >= t)) break;
          __builtin_amdgcn_s_sleep(2);
        }
        if (lane == 0)
          __hip_atomic_store(&go[t], 1, __ATOMIC_RELAXED,
                             __HIP_MEMORY_SCOPE_WORKGROUP);
      } else {
        while (__hip_atomic_load(&go[t], __ATOMIC_RELAXED,
                                 __HIP_MEMORY_SCOPE_WORKGROUP) == 0)
          __builtin_amdgcn_s_sleep(1);
      }
    }
    if (active) {
      const float* pt = P + (size_t)t * G4;
      float g0, g1, g2, g3;
      if (t == 0) {
        g0 = pt[n]; g1 = pt[NN + n]; g2 = pt[2 * NN + n]; g3 = pt[3 * NN + n];
      } else {
        const float* hrow = Hall + (size_t)(t - 1) * HPAD;
        float hg[16];
#pragma unroll
        for (int it = 0; it < 16; it++)  // 16 independent LLC loads in flight
          hg[it] = __hip_atomic_load(&hrow[it * 64 + lane], __ATOMIC_RELAXED,
                                     __HIP_MEMORY_SCOPE_AGENT);
        float a0 = 0.f, a1 = 0.f, a2 = 0.f, a3 = 0.f;
#pragma unroll
        for (int it = 0; it < 16; it++) {
          a0 += wreg[0][it] * hg[it];
          a1 += wreg[1][it] * hg[it];
          a2 += wreg[2][it] * hg[it];
          a3 += wreg[3][it] * hg[it];
        }
#pragma unroll
        for (int o = 32; o; o >>= 1) {
          a0 += __shfl_xor(a0, o);
          a1 += __shfl_xor(a1, o);
          a2 += __shfl_xor(a2, o);
          a3 += __shfl_xor(a3, o);
        }
        g0 = a0 + pt[n]; g1 = a1 + pt[NN + n];
        g2 = a2 + pt[2 * NN + n]; g3 = a3 + pt[3 * NN + n];
      }
      float ii = 1.f / (1.f + expf(-g0));
      float ff = 1.f / (1.f + expf(-g1));
      float gg = tanhf(g2);
      float oo = 1.f / (1.f + expf(-g3));
      creg = ff * creg + ii * gg;
      float h = oo * tanhf(creg);
      if (lane == 0)
        __hip_atomic_store(&Hall[(size_t)t * HPAD + n], h, __ATOMIC_RELAXED,
                           __HIP_MEMORY_SCOPE_AGENT);
    }
    // Own h store acknowledged at LLC before counting this wave as done.
    asm volatile("s_waitcnt vmcnt(0)" ::: "memory");
    if (lane == 0) {
      int prev = atomicAdd(&done[t], 1);
      if (prev == 15)
        __hip_atomic_store(&flag[blockIdx.x], t + 1, __ATOMIC_RELAXED,
                           __HIP_MEMORY_SCOPE_AGENT);
    }
  }
}

// Per-timestep output: min/max normalize + floored exp IRF. One block per t.
__global__ __launch_bounds__(256) void epilogue_out(
    const float* __restrict__ H7,   // [QQ, HPAD]
    const float* __restrict__ Wlin, const float* __restrict__ blin,
    const int* __restrict__ ccol, const float* __restrict__ Dnz,
    float* __restrict__ out,        // [QQ, NN]
    float* __restrict__ irbuf, float* __restrict__ mnirbuf) {
  int t = blockIdx.x, tid = threadIdx.x;
  int wave = tid >> 6, lane = tid & 63;
  __shared__ float hbuf[NN];
  __shared__ float smin[4], smax[4];
  __shared__ float bc[2];
  float lmin = 3.4e38f, lmax = -3.4e38f;
  for (int i = tid; i < NN; i += 256) {
    float v = H7[(size_t)t * HPAD + i];
    hbuf[i] = v;
    lmin = fminf(lmin, v); lmax = fmaxf(lmax, v);
  }
  lmin = wred_min(lmin); lmax = wred_max(lmax);
  if (lane == 0) { smin[wave] = lmin; smax[wave] = lmax; }
  __syncthreads();
  if (tid == 0) {
    bc[0] = fminf(fminf(smin[0], smin[1]), fminf(smin[2], smin[3]));
    bc[1] = fmaxf(fmaxf(smax[0], smax[1]), fmaxf(smax[2], smax[3]));
  }
  __syncthreads();
  float hmn = bc[0], hmx = bc[1];
  float clo = 3.4e38f, chi = -3.4e38f;
  if (tid < CCON) {
    float w = Wlin[tid], b = blin[tid];
    clo = b + fminf(w * hmn, w * hmx);
    chi = b + fmaxf(w * hmn, w * hmx);
  }
  clo = wred_min(clo); chi = wred_max(chi);
  __syncthreads();  // smin/smax reused below
  if (lane == 0) { smin[wave] = clo; smax[wave] = chi; }
  __syncthreads();
  if (tid == 0) {
    float mn = fminf(fminf(smin[0], smin[1]), fminf(smin[2], smin[3]));
    float mx = fmaxf(fmaxf(smax[0], smax[1]), fmaxf(smax[2], smax[3]));
    float ir = 1.f / (mx - mn);
    bc[0] = mn; bc[1] = ir;
    irbuf[t] = ir;
    mnirbuf[t] = mn * ir;
  }
  __syncthreads();
  float mn = bc[0], ir = bc[1];
  int cc = ccol[t];
  float wcc = Wlin[cc], bcc = blin[cc], d = Dnz[t];
  for (int n = tid; n < NN; n += 256) {
    float s = (hbuf[n] * wcc + bcc - mn) * ir;
    out[(size_t)t * NN + n] = fmaxf(0.25f, 1.f - expf(-10.f * (s - d)));
  }
}

__global__ void reduce_scalars(const float* __restrict__ ir,
                               const float* __restrict__ mnir,
                               float* __restrict__ scal) {
  int tid = threadIdx.x;  // 512
  int wave = tid >> 6, lane = tid & 63;
  __shared__ float s1[8], s2[8];
  float a = ir[tid], b = mnir[tid];
  a = wred_sum(a); b = wred_sum(b);
  if (lane == 0) { s1[wave] = a; s2[wave] = b; }
  __syncthreads();
  if (tid == 0) {
    float A = 0.f, B = 0.f;
    for (int i = 0; i < 8; i++) { A += s1[i]; B += s2[i]; }
    scal[0] = A; scal[1] = B;
  }
}

__global__ void accum_A(const float* __restrict__ H7,
                        const float* __restrict__ ir,
                        float* __restrict__ Avec) {
  int n = blockIdx.x * 256 + threadIdx.x;
  if (n < NN) {
    float acc = 0.f;
    for (int t = 0; t < QQ; t++) acc += H7[(size_t)t * HPAD + n] * ir[t];
    Avec[n] = acc;
  }
}

__global__ void skills_out(const float* __restrict__ Avec,
                           const float* __restrict__ Wlin,
                           const float* __restrict__ blin,
                           const float* __restrict__ scal,
                           float* __restrict__ out) {  // [NN, CCON]
  int idx = blockIdx.x * 256 + threadIdx.x;
  if (idx < NN * CCON) {
    int n = idx >> 7, c = idx & 127;
    out[idx] = (Wlin[c] * Avec[n] + blin[c] * scal[0] - scal[1]) * (1.f / (float)QQ);
  }
}

extern "C" void kernel_launch(void* const* d_in, const int* in_sizes, int n_in,
                              void* d_out, int out_size, void* d_ws, size_t ws_size,
                              hipStream_t stream) {
  const float* inputs = (const float*)d_in[0];
  const int*   ccol   = (const int*)d_in[1];
  const float* W_inp  = (const float*)d_in[2];
  const float* b_inp  = (const float*)d_in[3];
  const float* W_ih0  = (const float*)d_in[4];
  const float* W_hh0  = (const float*)d_in[5];
  const float* b_ih0  = (const float*)d_in[6];
  const float* b_hh0  = (const float*)d_in[7];
  const float* W_ih   = (const float*)d_in[8];   // [7, 4000, 1000]
  const float* W_hh   = (const float*)d_in[9];   // [7, 4000, 1000]
  const float* b_ih   = (const float*)d_in[10];  // [7, 4000]
  const float* b_hh   = (const float*)d_in[11];  // [7, 4000]
  const float* W_lin  = (const float*)d_in[12];  // [128]
  const float* b_lin  = (const float*)d_in[13];  // [128]
  const float* D_nz   = (const float*)d_in[14];  // [512]

  float* ws = (float*)d_ws;
  float* X    = ws;                       // [512,1024]
  float* P    = X + (size_t)QQ * HHID;    // [512,4000]
  float* H0   = P + (size_t)QQ * G4;      // [512,1024] padded
  float* H1   = H0 + (size_t)QQ * HPAD;   // [512,1024] padded
  float* irb  = H1 + (size_t)QQ * HPAD;   // [512]
  float* mnir = irb + QQ;                 // [512]
  float* Avec = mnir + QQ;                // [1024]
  float* scal = Avec + 1024;              // [2]
  int*   flags = (int*)(scal + 16);       // [8][64] per-layer stamped flags

  float* out_main   = (float*)d_out;            // [512,1000]
  float* out_skills = (float*)d_out + QQ * NN;  // [1000,128]

  // One small memset per launch (captured in the graph): all layer flags.
  hipMemsetAsync(flags, 0, 8 * 64 * sizeof(int), stream);

  // X = inputs @ W_inp^T + b_inp   (M=512, K=1000, R=1024)
  gemm_nt<<<dim3(HHID / 64, QQ / 64), 256, 0, stream>>>(
      inputs, W_inp, b_inp, nullptr, X, QQ, NN, HHID, NN);
  // P0 = X @ W_ih0^T + b_ih0 + b_hh0   (M=512, K=1024, R=4000)
  gemm_nt<<<dim3((G4 + 63) / 64, QQ / 64), 256, 0, stream>>>(
      X, W_ih0, b_ih0, b_hh0, P, QQ, HHID, G4, HHID);
  lstm_layer<<<LBLK, 1024, 0, stream>>>(P, W_hh0, H0, flags);

  for (int l = 1; l < 8; l++) {
    float* Hprev = ((l - 1) & 1) ? H1 : H0;
    float* Hcur  = (l & 1) ? H1 : H0;
    const float* wih = W_ih + (size_t)(l - 1) * G4 * NN;
    const float* whh = W_hh + (size_t)(l - 1) * G4 * NN;
    gemm_nt<<<dim3((G4 + 63) / 64, QQ / 64), 256, 0, stream>>>(
        Hprev, wih, b_ih + (size_t)(l - 1) * G4, b_hh + (size_t)(l - 1) * G4,
        P, QQ, NN, G4, HPAD);
    lstm_layer<<<LBLK, 1024, 0, stream>>>(P, whh, Hcur, flags + l * 64);
  }
  float* H7 = H1;  // layer 7 writes H1

  epilogue_out<<<QQ, 256, 0, stream>>>(H7, W_lin, b_lin, ccol, D_nz,
                                       out_main, irb, mnir);
  reduce_scalars<<<1, 512, 0, stream>>>(irb, mnir, scal);
  accum_A<<<4, 256, 0, stream>>>(H7, irb, Avec);
  skills_out<<<(NN * CCON) / 256, 256, 0, stream>>>(Avec, W_lin, b_lin, scal,
                                                    out_skills);
}

// Round 6
// 16757.834 us; speedup vs baseline: 1.3234x; 1.3234x over previous
//
#include <hip/hip_runtime.h>
#include <math.h>

#define QQ 512
#define NN 1000
#define HHID 1024
#define HPAD 1024   // padded row stride for h trajectories
#define CCON 128
#define G4 4000
#define LBLK 63     // ceil(1000/16) persistent blocks, 1024 thr, 1 neuron/wave

__device__ inline float wred_min(float v){ for(int o=32;o;o>>=1) v=fminf(v,__shfl_xor(v,o)); return v; }
__device__ inline float wred_max(float v){ for(int o=32;o;o>>=1) v=fmaxf(v,__shfl_xor(v,o)); return v; }
__device__ inline float wred_sum(float v){ for(int o=32;o;o>>=1) v+=__shfl_xor(v,o); return v; }

// C[M,R] = A[M,K] @ B[R,K]^T + bias1[r] + bias2[r]; A row stride = lda.
__global__ __launch_bounds__(256) void gemm_nt(
    const float* __restrict__ A, const float* __restrict__ B,
    const float* __restrict__ bias1, const float* __restrict__ bias2,
    float* __restrict__ C, int M, int K, int R, int lda) {
  __shared__ float As[16][65];
  __shared__ float Bs[16][65];
  int tid = threadIdx.x;
  int tx = tid & 15, ty = tid >> 4;
  int m0 = blockIdx.y * 64, r0 = blockIdx.x * 64;
  float acc[4][4] = {};
  for (int k0 = 0; k0 < K; k0 += 16) {
#pragma unroll
    for (int i = 0; i < 4; i++) {
      int idx = tid + 256 * i;
      int ml = idx >> 4, kl = idx & 15;
      int m = m0 + ml, k = k0 + kl;
      As[kl][ml] = (m < M && k < K) ? A[(size_t)m * lda + k] : 0.f;
      int r = r0 + ml;
      Bs[kl][ml] = (r < R && k < K) ? B[(size_t)r * K + k] : 0.f;
    }
    __syncthreads();
#pragma unroll
    for (int kk = 0; kk < 16; kk++) {
      float a[4], b[4];
#pragma unroll
      for (int i = 0; i < 4; i++) a[i] = As[kk][ty * 4 + i];
#pragma unroll
      for (int j = 0; j < 4; j++) b[j] = Bs[kk][tx * 4 + j];
#pragma unroll
      for (int i = 0; i < 4; i++)
#pragma unroll
        for (int j = 0; j < 4; j++) acc[i][j] += a[i] * b[j];
    }
    __syncthreads();
  }
#pragma unroll
  for (int i = 0; i < 4; i++) {
    int m = m0 + ty * 4 + i;
    if (m >= M) continue;
#pragma unroll
    for (int j = 0; j < 4; j++) {
      int r = r0 + tx * 4 + j;
      if (r >= R) continue;
      float v = acc[i][j];
      if (bias1) v += bias1[r];
      if (bias2) v += bias2[r];
      C[(size_t)m * R + r] = v;
    }
  }
}

// Persistent per-layer LSTM recurrence: all 512 timesteps in one launch.
// 63 blocks x 1024 threads; wave w owns neuron n = blockIdx*16 + w, holding
// its 4 W_hh rows in 64 VGPRs. Round-4 structure (LDS h broadcast) with
// stamped per-block flags: publish is a plain relaxed sc1 store to own slot
// (no RMW serialization); poll reads 63 contiguous dwords with one wave.
// No fences anywhere (agent acquire fence = buffer_inv = full L2 inval).
__global__ __launch_bounds__(1024, 4) void lstm_layer(
    const float* __restrict__ P,    // [QQ, G4] input-side gates (bias incl.)
    const float* __restrict__ Whh,  // [G4, NN]
    float* __restrict__ Hall,       // [QQ, HPAD]
    int* __restrict__ flag) {       // [64] zeroed before launch
  __shared__ float hs[1024];
  int tid = threadIdx.x;
  int wave = tid >> 6, lane = tid & 63;
  int n = blockIdx.x * 16 + wave;
  bool active = (n < NN);

  // Preload W_hh rows: wreg[q][it] = Whh[q*1000+n][it*64+lane]
  float wreg[4][16];
  if (active) {
#pragma unroll
    for (int q = 0; q < 4; q++) {
      const float* wrow = Whh + (size_t)(q * NN + n) * NN;
#pragma unroll
      for (int it = 0; it < 16; it++) {
        int k = it * 64 + lane;
        wreg[q][it] = (k < NN) ? wrow[k] : 0.f;
      }
    }
  } else {
#pragma unroll
    for (int q = 0; q < 4; q++)
#pragma unroll
      for (int it = 0; it < 16; it++) wreg[q][it] = 0.f;
  }
  if (tid >= NN) hs[tid] = 0.f;  // zero pad 1000..1023 once

  float creg = 0.f;  // cell state, register-resident for all 512 steps

  for (int t = 0; t < QQ; t++) {
    // Prefetch input-side gates for this step BEFORE waiting: their L2
    // latency overlaps the poll instead of following it.
    const float* pt = P + (size_t)t * G4;
    float p0 = 0.f, p1 = 0.f, p2 = 0.f, p3 = 0.f;
    if (active) {
      p0 = pt[n]; p1 = pt[NN + n]; p2 = pt[2 * NN + n]; p3 = pt[3 * NN + n];
    }
    if (t > 0) {
      // Wait until all 63 blocks published h[t-1] (flag[b] >= t).
      for (;;) {
        int v = t;
        if (tid < LBLK)
          v = __hip_atomic_load(&flag[tid], __ATOMIC_RELAXED,
                                __HIP_MEMORY_SCOPE_AGENT);
        if (__syncthreads_and(v >= t)) break;
        __builtin_amdgcn_s_sleep(2);
      }
      if (tid < NN)
        hs[tid] = __hip_atomic_load(&Hall[(size_t)(t - 1) * HPAD + tid],
                                    __ATOMIC_RELAXED, __HIP_MEMORY_SCOPE_AGENT);
      __syncthreads();
    }
    if (active) {
      float g0, g1, g2, g3;
      if (t == 0) {
        g0 = p0; g1 = p1; g2 = p2; g3 = p3;
      } else {
        float a0 = 0.f, a1 = 0.f, a2 = 0.f, a3 = 0.f;
#pragma unroll
        for (int it = 0; it < 16; it++) {
          float hv = hs[it * 64 + lane];
          a0 += wreg[0][it] * hv;
          a1 += wreg[1][it] * hv;
          a2 += wreg[2][it] * hv;
          a3 += wreg[3][it] * hv;
        }
#pragma unroll
        for (int o = 32; o; o >>= 1) {
          a0 += __shfl_xor(a0, o);
          a1 += __shfl_xor(a1, o);
          a2 += __shfl_xor(a2, o);
          a3 += __shfl_xor(a3, o);
        }
        g0 = a0 + p0; g1 = a1 + p1; g2 = a2 + p2; g3 = a3 + p3;
      }
      float ii = 1.f / (1.f + expf(-g0));
      float ff = 1.f / (1.f + expf(-g1));
      float gg = tanhf(g2);
      float oo = 1.f / (1.f + expf(-g3));
      creg = ff * creg + ii * gg;
      float h = oo * tanhf(creg);
      if (lane == 0)
        __hip_atomic_store(&Hall[(size_t)t * HPAD + n], h, __ATOMIC_RELAXED,
                           __HIP_MEMORY_SCOPE_AGENT);
    }
    __syncthreads();  // every wave drains vmcnt(0) before s_barrier -> h @ LLC
    if (tid == 0)
      __hip_atomic_store(&flag[blockIdx.x], t + 1, __ATOMIC_RELAXED,
                         __HIP_MEMORY_SCOPE_AGENT);
  }
}

// Per-timestep output: min/max normalize + floored exp IRF. One block per t.
__global__ __launch_bounds__(256) void epilogue_out(
    const float* __restrict__ H7,   // [QQ, HPAD]
    const float* __restrict__ Wlin, const float* __restrict__ blin,
    const int* __restrict__ ccol, const float* __restrict__ Dnz,
    float* __restrict__ out,        // [QQ, NN]
    float* __restrict__ irbuf, float* __restrict__ mnirbuf) {
  int t = blockIdx.x, tid = threadIdx.x;
  int wave = tid >> 6, lane = tid & 63;
  __shared__ float hbuf[NN];
  __shared__ float smin[4], smax[4];
  __shared__ float bc[2];
  float lmin = 3.4e38f, lmax = -3.4e38f;
  for (int i = tid; i < NN; i += 256) {
    float v = H7[(size_t)t * HPAD + i];
    hbuf[i] = v;
    lmin = fminf(lmin, v); lmax = fmaxf(lmax, v);
  }
  lmin = wred_min(lmin); lmax = wred_max(lmax);
  if (lane == 0) { smin[wave] = lmin; smax[wave] = lmax; }
  __syncthreads();
  if (tid == 0) {
    bc[0] = fminf(fminf(smin[0], smin[1]), fminf(smin[2], smin[3]));
    bc[1] = fmaxf(fmaxf(smax[0], smax[1]), fmaxf(smax[2], smax[3]));
  }
  __syncthreads();
  float hmn = bc[0], hmx = bc[1];
  float clo = 3.4e38f, chi = -3.4e38f;
  if (tid < CCON) {
    float w = Wlin[tid], b = blin[tid];
    clo = b + fminf(w * hmn, w * hmx);
    chi = b + fmaxf(w * hmn, w * hmx);
  }
  clo = wred_min(clo); chi = wred_max(chi);
  __syncthreads();  // smin/smax reused below
  if (lane == 0) { smin[wave] = clo; smax[wave] = chi; }
  __syncthreads();
  if (tid == 0) {
    float mn = fminf(fminf(smin[0], smin[1]), fminf(smin[2], smin[3]));
    float mx = fmaxf(fmaxf(smax[0], smax[1]), fmaxf(smax[2], smax[3]));
    float ir = 1.f / (mx - mn);
    bc[0] = mn; bc[1] = ir;
    irbuf[t] = ir;
    mnirbuf[t] = mn * ir;
  }
  __syncthreads();
  float mn = bc[0], ir = bc[1];
  int cc = ccol[t];
  float wcc = Wlin[cc], bcc = blin[cc], d = Dnz[t];
  for (int n = tid; n < NN; n += 256) {
    float s = (hbuf[n] * wcc + bcc - mn) * ir;
    out[(size_t)t * NN + n] = fmaxf(0.25f, 1.f - expf(-10.f * (s - d)));
  }
}

__global__ void reduce_scalars(const float* __restrict__ ir,
                               const float* __restrict__ mnir,
                               float* __restrict__ scal) {
  int tid = threadIdx.x;  // 512
  int wave = tid >> 6, lane = tid & 63;
  __shared__ float s1[8], s2[8];
  float a = ir[tid], b = mnir[tid];
  a = wred_sum(a); b = wred_sum(b);
  if (lane == 0) { s1[wave] = a; s2[wave] = b; }
  __syncthreads();
  if (tid == 0) {
    float A = 0.f, B = 0.f;
    for (int i = 0; i < 8; i++) { A += s1[i]; B += s2[i]; }
    scal[0] = A; scal[1] = B;
  }
}

__global__ void accum_A(const float* __restrict__ H7,
                        const float* __restrict__ ir,
                        float* __restrict__ Avec) {
  int n = blockIdx.x * 256 + threadIdx.x;
  if (n < NN) {
    float acc = 0.f;
    for (int t = 0; t < QQ; t++) acc += H7[(size_t)t * HPAD + n] * ir[t];
    Avec[n] = acc;
  }
}

__global__ void skills_out(const float* __restrict__ Avec,
                           const float* __restrict__ Wlin,
                           const float* __restrict__ blin,
                           const float* __restrict__ scal,
                           float* __restrict__ out) {  // [NN, CCON]
  int idx = blockIdx.x * 256 + threadIdx.x;
  if (idx < NN * CCON) {
    int n = idx >> 7, c = idx & 127;
    out[idx] = (Wlin[c] * Avec[n] + blin[c] * scal[0] - scal[1]) * (1.f / (float)QQ);
  }
}

extern "C" void kernel_launch(void* const* d_in, const int* in_sizes, int n_in,
                              void* d_out, int out_size, void* d_ws, size_t ws_size,
                              hipStream_t stream) {
  const float* inputs = (const float*)d_in[0];
  const int*   ccol   = (const int*)d_in[1];
  const float* W_inp  = (const float*)d_in[2];
  const float* b_inp  = (const float*)d_in[3];
  const float* W_ih0  = (const float*)d_in[4];
  const float* W_hh0  = (const float*)d_in[5];
  const float* b_ih0  = (const float*)d_in[6];
  const float* b_hh0  = (const float*)d_in[7];
  const float* W_ih   = (const float*)d_in[8];   // [7, 4000, 1000]
  const float* W_hh   = (const float*)d_in[9];   // [7, 4000, 1000]
  const float* b_ih   = (const float*)d_in[10];  // [7, 4000]
  const float* b_hh   = (const float*)d_in[11];  // [7, 4000]
  const float* W_lin  = (const float*)d_in[12];  // [128]
  const float* b_lin  = (const float*)d_in[13];  // [128]
  const float* D_nz   = (const float*)d_in[14];  // [512]

  float* ws = (float*)d_ws;
  float* X    = ws;                       // [512,1024]
  float* P    = X + (size_t)QQ * HHID;    // [512,4000]
  float* H0   = P + (size_t)QQ * G4;      // [512,1024] padded
  float* H1   = H0 + (size_t)QQ * HPAD;   // [512,1024] padded
  float* irb  = H1 + (size_t)QQ * HPAD;   // [512]
  float* mnir = irb + QQ;                 // [512]
  float* Avec = mnir + QQ;                // [1024]
  float* scal = Avec + 1024;              // [2]
  int*   flags = (int*)(scal + 16);       // [8][64] per-layer stamped flags

  float* out_main   = (float*)d_out;            // [512,1000]
  float* out_skills = (float*)d_out + QQ * NN;  // [1000,128]

  // One small memset per launch (captured in the graph): all layer flags.
  hipMemsetAsync(flags, 0, 8 * 64 * sizeof(int), stream);

  // X = inputs @ W_inp^T + b_inp   (M=512, K=1000, R=1024)
  gemm_nt<<<dim3(HHID / 64, QQ / 64), 256, 0, stream>>>(
      inputs, W_inp, b_inp, nullptr, X, QQ, NN, HHID, NN);
  // P0 = X @ W_ih0^T + b_ih0 + b_hh0   (M=512, K=1024, R=4000)
  gemm_nt<<<dim3((G4 + 63) / 64, QQ / 64), 256, 0, stream>>>(
      X, W_ih0, b_ih0, b_hh0, P, QQ, HHID, G4, HHID);
  lstm_layer<<<LBLK, 1024, 0, stream>>>(P, W_hh0, H0, flags);

  for (int l = 1; l < 8; l++) {
    float* Hprev = ((l - 1) & 1) ? H1 : H0;
    float* Hcur  = (l & 1) ? H1 : H0;
    const float* wih = W_ih + (size_t)(l - 1) * G4 * NN;
    const float* whh = W_hh + (size_t)(l - 1) * G4 * NN;
    gemm_nt<<<dim3((G4 + 63) / 64, QQ / 64), 256, 0, stream>>>(
        Hprev, wih, b_ih + (size_t)(l - 1) * G4, b_hh + (size_t)(l - 1) * G4,
        P, QQ, NN, G4, HPAD);
    lstm_layer<<<LBLK, 1024, 0, stream>>>(P, whh, Hcur, flags + l * 64);
  }
  float* H7 = H1;  // layer 7 writes H1

  epilogue_out<<<QQ, 256, 0, stream>>>(H7, W_lin, b_lin, ccol, D_nz,
                                       out_main, irb, mnir);
  reduce_scalars<<<1, 512, 0, stream>>>(irb, mnir, scal);
  accum_A<<<4, 256, 0, stream>>>(H7, irb, Avec);
  skills_out<<<(NN * CCON) / 256, 256, 0, stream>>>(Avec, W_lin, b_lin, scal,
                                                    out_skills);
}